// Round 17
// baseline (269.463 us; speedup 1.0000x reference)
//
#include <hip/hip_runtime.h>

// ---------------------------------------------------------------------------
// net_lstm: graph-constructor (topk-20 sparse adj) + per-node LSTM (bf16 MFMA)
//           + mixprop x2 (sparse gather + uniform-weight proj) + layernorm.
// Only layer j=2 of the 3 layers affects the output (reference overwrites h).
// ALL tensors are FLOAT32 on device. LSTM matmul in bf16 MFMA, rest fp32.
// k_lstm design notes (measured):
//  - 16 independent accumulators (64 AGPR) + 48 back-to-back MFMAs per step
//    beat a 16-AGPR low-ILP variant by 10% (r8 95.8 vs r9 105.5us).
//  - OCCUPANCY KNOB IS CLOSED: (256,4)->850MB spill (r7); (256,3)->7MB spill
//    +25% occupancy and still +11us SLOWER (r14). Stay (256,2), unified<=256.
//  - r10's raw asm("v_exp_f32") + weight pre-scaling produced zero output —
//    keep __expf; no hand-rolled trans asm.
// r17: 8 of 32 Whh fragment tiles (ks=0, nt 0..7) cached in REGISTERS
// (+32 VGPR -> ~220 unified, safe margin below 256 cap); per-step LDS reads
// 32 -> 24 b128. Abort signature if wrong: WRITE_SIZE >> 3.3MB (spill).
// ---------------------------------------------------------------------------

typedef unsigned short u16;
typedef __attribute__((ext_vector_type(8))) short bf16x8;   // 8 bf16 = 4 VGPR (MFMA A/B frag)
typedef __attribute__((ext_vector_type(4))) float fx4;      // MFMA C/D frag

#define NB 64          // batch
#define NNODE 1000
#define TT 12
#define FF 32
#define HH 64
#define DD 40
#define TOPK_ 20
#define EPR2 22        // adjacency entries per row: topk + diagonal + 1 pad (16B align)

__device__ __forceinline__ float rcp_f(float x) { return __builtin_amdgcn_rcpf(x); }
__device__ __forceinline__ float tanh_f(float x) {          // NaN-safe: e>=0 always
  return fmaf(-2.0f, rcp_f(__expf(2.0f * x) + 1.0f), 1.0f);
}
__device__ __forceinline__ unsigned int cvt_pk(float lo, float hi) {
  unsigned int r;                                           // r = [bf16(hi)|bf16(lo)]
  asm("v_cvt_pk_bf16_f32 %0, %1, %2" : "=v"(r) : "v"(lo), "v"(hi));
  return r;
}
__device__ __forceinline__ bf16x8 cvt8(const float* p) {    // 8 fp32 -> bf16x8 (4 cvt_pk)
  union { unsigned int u[4]; bf16x8 v; } r;
  #pragma unroll
  for (int e = 0; e < 4; e++) r.u[e] = cvt_pk(p[2 * e], p[2 * e + 1]);
  return r.v;
}
__device__ __forceinline__ bf16x8 cvt8v(float4 a, float4 b) {
  union { unsigned int u[4]; bf16x8 v; } r;
  r.u[0] = cvt_pk(a.x, a.y); r.u[1] = cvt_pk(a.z, a.w);
  r.u[2] = cvt_pk(b.x, b.y); r.u[3] = cvt_pk(b.z, b.w);
  return r.v;
}

// ---------------- K3+K1: fused LSTM (blocks 0..999) & m1m2/prep (1000..1313) -
__global__ __launch_bounds__(256, 2)
void k_lstm(const float* __restrict__ x, const float* __restrict__ Wih,
            const float* __restrict__ Whh, const float* __restrict__ bih,
            const float* __restrict__ bhh, const float* __restrict__ lw2,
            const float* __restrict__ lb2, float* __restrict__ hj,
            // m1m2/prep path:
            const float* __restrict__ emb1, const float* __restrict__ emb2,
            const float* __restrict__ w1, const float* __restrict__ b1,
            const float* __restrict__ w2, const float* __restrict__ b2,
            float* __restrict__ m1, float* __restrict__ m2,
            const float* __restrict__ p1w, const float* __restrict__ p1b,
            const float* __restrict__ p2w, const float* __restrict__ p2b,
            float* __restrict__ wt) {
  int tid = threadIdx.x;
  if (blockIdx.x >= 1000) {              // ---- m1m2 / prep path ----
    int mb = blockIdx.x - 1000;
    if (mb == 313) {                     // prep: proj weights transposed
      for (int i = tid; i < 1152; i += 256) { int c = i / 32, o = i % 32; wt[784 + i] = p1w[o * 36 + c]; }
      if (tid < 32) wt[1936 + tid] = p1b[tid];
      for (int i = tid; i < 3840; i += 256) { int c = i / 40, o = i % 40; wt[1968 + i] = p2w[o * 96 + c]; }
      if (tid < 40) wt[5808 + tid] = p2b[tid];
      return;
    }
    int id = mb * 256 + tid;
    if (id >= 2 * NNODE * DD) return;
    int sel = id / (NNODE * DD);
    int r = id % (NNODE * DD);
    int i = r / DD, o = r % DD;
    const float4* emb = (const float4*)((sel ? emb2 : emb1) + i * DD);
    const float4* w = (const float4*)((sel ? w2 : w1) + o * DD);
    float s = (sel ? b2 : b1)[o];
    #pragma unroll
    for (int k4 = 0; k4 < DD / 4; k4++) {
      float4 a = emb[k4], b = w[k4];
      s = fmaf(a.x, b.x, s); s = fmaf(a.y, b.y, s);
      s = fmaf(a.z, b.z, s); s = fmaf(a.w, b.w, s);
    }
    (sel ? m2 : m1)[r] = tanh_f(3.0f * s);
    return;
  }
  // ---- LSTM path ----
  __shared__ __align__(16) u16 whf[2 * 16 * 64 * 8];  // Whh frags (32 KB)
  __shared__ __align__(16) u16 hsh[4][16][64];        // per-wave h shuttle (8 KB)
  __shared__ float lwsh[12 * 64];                     // lin_w2 [s][j] (3 KB)
  __shared__ float lbsh[12];
  int wave = tid >> 6, lane = tid & 63;
  int arow = lane & 15, kg = lane >> 4;

  for (int cc = tid; cc < 2 * 16 * 64; cc += 256) {
    int l = cc & 63, t16 = cc >> 6, ks = t16 >> 4, nt = t16 & 15;
    int row = (nt >> 2) * 64 + (l & 15) * 4 + (nt & 3);
    *(bf16x8*)&whf[cc * 8] = cvt8(Whh + row * 64 + ks * 32 + (l >> 4) * 8);
  }
  for (int i = tid; i < 768; i += 256) lwsh[i] = lw2[i];   // identity map
  if (tid < 12) lbsh[tid] = lb2[tid];
  __syncthreads();                                    // the ONLY block barrier

  bf16x8 wi[16];
  float biasv[16];
  #pragma unroll
  for (int nt = 0; nt < 16; nt++) {
    int row = (nt >> 2) * 64 + arow * 4 + (nt & 3);
    wi[nt] = cvt8(Wih + row * 32 + kg * 8);
    biasv[nt] = bih[row] + bhh[row];
  }
  bf16x8 wh0[8];                         // ks=0, nt 0..7 tiles cached in regs
  #pragma unroll
  for (int nt = 0; nt < 8; nt++)
    wh0[nt] = *(const bf16x8*)&whf[(nt * 64 + lane) * 8];

  int seq_base = blockIdx.x * 64 + wave * 16;
  const float* xb = x + (size_t)(seq_base + arow) * (TT * FF) + kg * 8;
  float cst[16];
  #pragma unroll
  for (int q = 0; q < 16; q++) cst[q] = 0.f;

  float4 xf0 = *(const float4*)(xb);                  // prefetch t=0
  float4 xf1 = *(const float4*)(xb + 4);

  auto STEP = [&](int t, bool first, float (&hq)[16]) {
    unsigned int zo = 0;                 // opaque zero: whf addrs loop-variant
    asm volatile("" : "+v"(zo));
    bf16x8 xa = cvt8v(xf0, xf1);
    if (t < TT - 1) {
      xf0 = *(const float4*)(xb + (t + 1) * FF);
      xf1 = *(const float4*)(xb + (t + 1) * FF + 4);
    }
    fx4 acc[16];
    #pragma unroll
    for (int nt = 0; nt < 16; nt++)
      acc[nt] = (fx4){biasv[nt], biasv[nt], biasv[nt], biasv[nt]};
    #pragma unroll
    for (int nt = 0; nt < 16; nt++)
      acc[nt] = __builtin_amdgcn_mfma_f32_16x16x32_bf16(xa, wi[nt], acc[nt], 0, 0, 0);
    if (!first) {
      asm volatile("" ::: "memory");
      bf16x8 ha0 = *(const bf16x8*)&hsh[wave][arow][kg * 8];
      bf16x8 ha1 = *(const bf16x8*)&hsh[wave][arow][32 + kg * 8];
      asm volatile("" ::: "memory");
      #pragma unroll
      for (int nt = 0; nt < 8; nt++)     // ks=0, nt 0..7 from registers
        acc[nt] = __builtin_amdgcn_mfma_f32_16x16x32_bf16(ha0, wh0[nt], acc[nt], 0, 0, 0);
      #pragma unroll
      for (int nt = 8; nt < 16; nt++) {  // ks=0, nt 8..15 from LDS
        bf16x8 wb = *(const bf16x8*)&whf[(nt * 64 + lane) * 8 + zo];
        acc[nt] = __builtin_amdgcn_mfma_f32_16x16x32_bf16(ha0, wb, acc[nt], 0, 0, 0);
      }
      #pragma unroll
      for (int nt = 0; nt < 16; nt++) {  // ks=1 slab from LDS
        bf16x8 wb = *(const bf16x8*)&whf[((16 + nt) * 64 + lane) * 8 + zo];
        acc[nt] = __builtin_amdgcn_mfma_f32_16x16x32_bf16(ha1, wb, acc[nt], 0, 0, 0);
      }
    }
    #pragma unroll
    for (int i = 0; i < 4; i++) {
      #pragma unroll
      for (int njt = 0; njt < 4; njt++) {
        float iv = acc[njt][i], fv = acc[njt + 4][i];
        float gv = acc[njt + 8][i], ov = acc[njt + 12][i];
        float cpv = cst[i * 4 + njt];
        float ei = __expf(-iv), ef = __expf(-fv);
        float eg = __expf(2.0f * gv), eo = __expf(-ov);
        float A = 1.0f + ef;
        float B = (1.0f + ei) * (eg + 1.0f);
        float c = fmaf(cpv, B, (eg - 1.0f) * A) * rcp_f(A * B);
        cst[i * 4 + njt] = c;
        float ec = __expf(2.0f * c);
        hq[i * 4 + njt] = (ec - 1.0f) * rcp_f((ec + 1.0f) * (1.0f + eo));
      }
    }
  };

  #pragma unroll 1
  for (int t = 0; t < TT - 1; t++) {
    float hq[16];
    STEP(t, t == 0, hq);
    #pragma unroll
    for (int i = 0; i < 4; i++) {
      unsigned int p0 = cvt_pk(hq[i * 4 + 0], hq[i * 4 + 1]);
      unsigned int p1 = cvt_pk(hq[i * 4 + 2], hq[i * 4 + 3]);
      *(uint2*)&hsh[wave][kg * 4 + i][arow * 4] = make_uint2(p0, p1);
    }
  }
  float hq[16];
  STEP(TT - 1, false, hq);

  #pragma unroll
  for (int i = 0; i < 4; i++) {
    float a[12];
    #pragma unroll
    for (int s = 0; s < 12; s++) a[s] = 0.f;
    #pragma unroll
    for (int njt = 0; njt < 4; njt++) {
      float hv = hq[i * 4 + njt];
      #pragma unroll
      for (int s = 0; s < 12; s++)
        a[s] = fmaf(hv, lwsh[s * 64 + arow * 4 + njt], a[s]);
    }
    #pragma unroll
    for (int off = 1; off < 16; off <<= 1) {
      #pragma unroll
      for (int s = 0; s < 12; s++) a[s] += __shfl_xor(a[s], off);
    }
    float outv = a[0];                   // static select chain (rule #20)
    #pragma unroll
    for (int s = 1; s < 12; s++) outv = (arow == s) ? a[s] : outv;
    if (arow < 12) {
      int gseq = seq_base + kg * 4 + i;
      int bb = gseq / 1000, nn = gseq - bb * 1000;
      hj[(size_t)(bb * 12 + arow) * NNODE + nn] = outv + lbsh[arow];
    }
  }
}

// ---------------- K2: adjacency, 4 rows per block ----------------------------
__global__ void k_adj(const float* __restrict__ m1, const float* __restrict__ m2,
                      int2* __restrict__ pae) {
  int v0 = blockIdx.x * 4, tid = threadIdx.x;
  int lane = tid & 63, wave = tid >> 6;
  __shared__ float arow4[4][1024];                    // 16 KB
  __shared__ float m1v4[4][DD], m2v4[4][DD];
  for (int i = tid; i < 4 * DD; i += 256) {
    int r = i / DD, k = i % DD;
    m1v4[r][k] = m1[(v0 + r) * DD + k];
    m2v4[r][k] = m2[(v0 + r) * DD + k];
  }
  __syncthreads();
  for (int w = tid; w < NNODE; w += 256) {
    const float4* m2r = (const float4*)(m2 + w * DD);
    const float4* m1r = (const float4*)(m1 + w * DD);
    float4 a[10], bb[10];
    #pragma unroll
    for (int k4 = 0; k4 < 10; k4++) { a[k4] = m2r[k4]; bb[k4] = m1r[k4]; }
    #pragma unroll
    for (int r = 0; r < 4; r++) {
      float d1 = 0.f, d2 = 0.f;
      #pragma unroll
      for (int k4 = 0; k4 < 10; k4++) {
        d1 = fmaf(m1v4[r][k4 * 4 + 0], a[k4].x, d1);
        d1 = fmaf(m1v4[r][k4 * 4 + 1], a[k4].y, d1);
        d1 = fmaf(m1v4[r][k4 * 4 + 2], a[k4].z, d1);
        d1 = fmaf(m1v4[r][k4 * 4 + 3], a[k4].w, d1);
        d2 = fmaf(m2v4[r][k4 * 4 + 0], bb[k4].x, d2);
        d2 = fmaf(m2v4[r][k4 * 4 + 1], bb[k4].y, d2);
        d2 = fmaf(m2v4[r][k4 * 4 + 2], bb[k4].z, d2);
        d2 = fmaf(m2v4[r][k4 * 4 + 3], bb[k4].w, d2);
      }
      arow4[r][w] = fmaxf(tanh_f(3.0f * (d1 - d2)), 0.0f);
    }
  }
  __syncthreads();
  int v = v0 + wave, l = lane;           // wave r selects for row v0+r
  float rv[16];
  #pragma unroll
  for (int q = 0; q < 16; q++) {
    int idx = q * 64 + l;
    rv[q] = (idx < NNODE) ? arow4[wave][idx] : -2.f;
  }
  float rs = 1.f;                        // diagonal contributes 1
  float myv = 0.f; int myi = 0;          // lane l carries selected entry (l-1)
  #pragma unroll
  for (int sel = 0; sel < TOPK_; sel++) {
    float bv = rv[0]; int bi = l;
    #pragma unroll
    for (int q = 1; q < 16; q++) {
      int idx = q * 64 + l;
      if (rv[q] > bv) { bv = rv[q]; bi = idx; }   // ascending q => lowest idx on tie
    }
    #pragma unroll
    for (int off = 1; off < 64; off <<= 1) {
      float ov = __shfl_xor(bv, off); int oi = __shfl_xor(bi, off);
      if (ov > bv || (ov == bv && oi < bi)) { bv = ov; bi = oi; }
    }
    rs += bv;
    if (l == sel + 1) { myv = bv; myi = bi; }
    #pragma unroll
    for (int q = 0; q < 16; q++)
      if (q * 64 + l == bi) rv[q] = -2.f;         // invalidate winner
  }
  float inv = rcp_f(rs);
  if (l == 0)          pae[v * EPR2] = make_int2(v, __float_as_int(inv));
  else if (l <= TOPK_) pae[v * EPR2 + l] = make_int2(myi, __float_as_int(myv * inv));
  else if (l == 21)    pae[v * EPR2 + 21] = make_int2(v, 0);   // pad: val 0
}

// ---------------- K5/K7: mixprop propagation, 4 channels per block ----------
__global__ void k_prop4(const float* __restrict__ hin, const int2* __restrict__ pae,
                        float* __restrict__ ho, int C) {
  int NG = C >> 2;
  int b = blockIdx.x / NG, g = blockIdx.x % NG;
  int c0 = g * 4;
  __shared__ float r0c[4][1024];                      // 16 KB
  __shared__ float r1c[4][1024];                      // 16 KB
  int tid = threadIdx.x;
  const float* src = hin + ((size_t)b * C + c0) * NNODE;
  float* dst = ho + (size_t)b * 2 * C * NNODE;
  for (int n = tid; n < NNODE; n += 256) {
    r0c[0][n] = src[n];
    r0c[1][n] = src[NNODE + n];
    r0c[2][n] = src[2 * NNODE + n];
    r0c[3][n] = src[3 * NNODE + n];
  }
  __syncthreads();
  for (int n = tid; n < NNODE; n += 256) {
    const int4* pa4 = (const int4*)(pae + (size_t)n * EPR2);
    float s0 = 0.f, s1 = 0.f, s2 = 0.f, s3 = 0.f;
    #pragma unroll
    for (int e = 0; e < EPR2 / 2; e++) {
      int4 p = pa4[e];
      float av = __int_as_float(p.y);
      s0 = fmaf(av, r0c[0][p.x], s0); s1 = fmaf(av, r0c[1][p.x], s1);
      s2 = fmaf(av, r0c[2][p.x], s2); s3 = fmaf(av, r0c[3][p.x], s3);
      float aw = __int_as_float(p.w);
      s0 = fmaf(aw, r0c[0][p.z], s0); s1 = fmaf(aw, r0c[1][p.z], s1);
      s2 = fmaf(aw, r0c[2][p.z], s2); s3 = fmaf(aw, r0c[3][p.z], s3);
    }
    float h10 = fmaf(0.95f, s0, 0.05f * r0c[0][n]);
    float h11 = fmaf(0.95f, s1, 0.05f * r0c[1][n]);
    float h12 = fmaf(0.95f, s2, 0.05f * r0c[2][n]);
    float h13 = fmaf(0.95f, s3, 0.05f * r0c[3][n]);
    r1c[0][n] = h10; r1c[1][n] = h11; r1c[2][n] = h12; r1c[3][n] = h13;
    dst[(size_t)(c0 + 0) * NNODE + n] = h10;
    dst[(size_t)(c0 + 1) * NNODE + n] = h11;
    dst[(size_t)(c0 + 2) * NNODE + n] = h12;
    dst[(size_t)(c0 + 3) * NNODE + n] = h13;
  }
  __syncthreads();
  for (int n = tid; n < NNODE; n += 256) {
    const int4* pa4 = (const int4*)(pae + (size_t)n * EPR2);
    float s0 = 0.f, s1 = 0.f, s2 = 0.f, s3 = 0.f;
    #pragma unroll
    for (int e = 0; e < EPR2 / 2; e++) {
      int4 p = pa4[e];
      float av = __int_as_float(p.y);
      s0 = fmaf(av, r1c[0][p.x], s0); s1 = fmaf(av, r1c[1][p.x], s1);
      s2 = fmaf(av, r1c[2][p.x], s2); s3 = fmaf(av, r1c[3][p.x], s3);
      float aw = __int_as_float(p.w);
      s0 = fmaf(aw, r1c[0][p.z], s0); s1 = fmaf(aw, r1c[1][p.z], s1);
      s2 = fmaf(aw, r1c[2][p.z], s2); s3 = fmaf(aw, r1c[3][p.z], s3);
    }
    dst[(size_t)(C + c0 + 0) * NNODE + n] = fmaf(0.95f, s0, 0.05f * r0c[0][n]);
    dst[(size_t)(C + c0 + 1) * NNODE + n] = fmaf(0.95f, s1, 0.05f * r0c[1][n]);
    dst[(size_t)(C + c0 + 2) * NNODE + n] = fmaf(0.95f, s2, 0.05f * r0c[2][n]);
    dst[(size_t)(C + c0 + 3) * NNODE + n] = fmaf(0.95f, s3, 0.05f * r0c[3][n]);
  }
}

// ---------------- K6/K8: channel projection -----------------------------------
template <int C1, int COUT>
__global__ void k_proj(const float* __restrict__ src0, const float* __restrict__ src12,
                       const float* __restrict__ wt, const float* __restrict__ bb,
                       float* __restrict__ out, int relu) {
  int id = blockIdx.x * 256 + threadIdx.x;   // (b,n)
  int b = id / NNODE, n = id % NNODE;
  float acc[COUT];
  #pragma unroll
  for (int o = 0; o < COUT; o++) acc[o] = bb[o];
  for (int c = 0; c < C1; c++) {
    float hv = src0[(size_t)(b * C1 + c) * NNODE + n];
    #pragma unroll
    for (int o = 0; o < COUT; o++) acc[o] = fmaf(hv, wt[c * COUT + o], acc[o]);
  }
  for (int c = 0; c < 2 * C1; c++) {
    float hv = src12[(size_t)(b * 2 * C1 + c) * NNODE + n];
    #pragma unroll
    for (int o = 0; o < COUT; o++) acc[o] = fmaf(hv, wt[(C1 + c) * COUT + o], acc[o]);
  }
  #pragma unroll
  for (int o = 0; o < COUT; o++) {
    float vv = acc[o];
    if (relu) vv = fmaxf(vv, 0.f);
    out[(size_t)(b * COUT + o) * NNODE + n] = vv;
  }
}

// ---------------- K9a: LN partial stats (4 blocks per batch) -----------------
__global__ void k_lnpart(const float* __restrict__ hj2, float* __restrict__ part) {
  int b = blockIdx.x >> 2, qt = blockIdx.x & 3;
  int tid = threadIdx.x, lane = tid & 63, wave = tid >> 6;
  const float4* p = (const float4*)(hj2 + (size_t)b * DD * NNODE) + qt * 2500;
  float s = 0.f, q = 0.f;
  for (int i = tid; i < 2500; i += 256) {
    float4 vv = p[i];
    s += vv.x + vv.y + vv.z + vv.w;
    q = fmaf(vv.x, vv.x, q); q = fmaf(vv.y, vv.y, q);
    q = fmaf(vv.z, vv.z, q); q = fmaf(vv.w, vv.w, q);
  }
  for (int off = 32; off; off >>= 1) { s += __shfl_down(s, off); q += __shfl_down(q, off); }
  __shared__ float ss[4], sq[4];
  if (lane == 0) { ss[wave] = s; sq[wave] = q; }
  __syncthreads();
  if (tid == 0) {
    part[b * 8 + qt] = (ss[0] + ss[1]) + (ss[2] + ss[3]);
    part[b * 8 + 4 + qt] = (sq[0] + sq[1]) + (sq[2] + sq[3]);
  }
}

// ---------------- K9b: LN apply (250 blocks; folds 4 partials inline) --------
__global__ void k_lnapply(const float* __restrict__ hj2, const float* __restrict__ part,
                          const float* __restrict__ gamma, const float* __restrict__ beta,
                          float* __restrict__ out) {
  int id = blockIdx.x * 256 + threadIdx.x;   // (b,n)
  int b = id / NNODE, n = id % NNODE;
  float S = (part[b * 8 + 0] + part[b * 8 + 1]) + (part[b * 8 + 2] + part[b * 8 + 3]);
  float Q = (part[b * 8 + 4] + part[b * 8 + 5]) + (part[b * 8 + 6] + part[b * 8 + 7]);
  const float invN = 1.0f / (float)(DD * NNODE);
  float mu = S * invN;
  float var = Q * invN - mu * mu;
  float rstd = __builtin_amdgcn_rsqf(var + 1e-5f);
  size_t obase = (size_t)b * (NNODE * DD) + (size_t)n * DD;
  #pragma unroll
  for (int d0 = 0; d0 < DD / 4; d0++) {
    float tt[4];
    #pragma unroll
    for (int qq = 0; qq < 4; qq++) {
      int d = d0 * 4 + qq;
      float h0 = hj2[(size_t)(b * DD + d) * NNODE + n];
      tt[qq] = (h0 - mu) * rstd * gamma[d * NNODE + n] + beta[d * NNODE + n];
    }
    *(float4*)(out + obase + d0 * 4) = (float4){tt[0], tt[1], tt[2], tt[3]};
  }
}

// ---------------- workspace layout (fp32 words, flat) ------------------------
#define OFF_M1   0
#define OFF_M2   40000
#define OFF_PAE  80000
#define OFF_HJ   124000
#define OFF_HO1  892000
#define OFF_O1   2428000
#define OFF_HO2  4476000
#define OFF_HJ2  8572000
#define OFF_PART 11132000
#define OFF_WT   11132512

extern "C" void kernel_launch(void* const* d_in, const int* in_sizes, int n_in,
                              void* d_out, int out_size, void* d_ws, size_t ws_size,
                              hipStream_t stream) {
  (void)in_sizes; (void)n_in; (void)out_size; (void)ws_size;
  const float* x     = (const float*)d_in[0];
  const float* emb1  = (const float*)d_in[1];
  const float* emb2  = (const float*)d_in[2];
  const float* l1w   = (const float*)d_in[3];
  const float* l1b   = (const float*)d_in[4];
  const float* l2w   = (const float*)d_in[5];
  const float* l2b   = (const float*)d_in[6];
  const float* Wih   = (const float*)d_in[7];
  const float* Whh   = (const float*)d_in[8];
  const float* bih   = (const float*)d_in[9];
  const float* bhh   = (const float*)d_in[10];
  const float* lin_w = (const float*)d_in[11];
  const float* lin_b = (const float*)d_in[12];
  const float* mp1w  = (const float*)d_in[13];
  const float* mp1b  = (const float*)d_in[14];
  const float* mp2w  = (const float*)d_in[15];
  const float* mp2b  = (const float*)d_in[16];
  const float* gamma = (const float*)d_in[17];
  const float* beta  = (const float*)d_in[18];

  float* ws   = (float*)d_ws;
  float* m1   = ws + OFF_M1;
  float* m2   = ws + OFF_M2;
  int2*  pae  = (int2*)(ws + OFF_PAE);
  float* hj   = ws + OFF_HJ;
  float* ho1  = ws + OFF_HO1;
  float* o1   = ws + OFF_O1;
  float* ho2  = ws + OFF_HO2;
  float* hj2  = ws + OFF_HJ2;
  float* part = ws + OFF_PART;
  float* wt   = ws + OFF_WT;

  k_lstm<<<dim3(1314), dim3(256), 0, stream>>>(x, Wih, Whh, bih, bhh,
                                               lin_w + 1536, lin_b + 24, hj,
                                               emb1, emb2, l1w, l1b, l2w, l2b, m1, m2,
                                               mp1w + 2304, mp1b + 64,
                                               mp2w + 7680, mp2b + 80, wt);
  k_adj<<<dim3(250), dim3(256), 0, stream>>>(m1, m2, pae);
  k_prop4<<<dim3(64 * 3), dim3(256), 0, stream>>>(hj, pae, ho1, 12);
  k_proj<12, 32><<<dim3(250), dim3(256), 0, stream>>>(hj, ho1, wt + 784, wt + 1936, o1, 1);
  k_prop4<<<dim3(64 * 8), dim3(256), 0, stream>>>(o1, pae, ho2, 32);
  k_proj<32, 40><<<dim3(250), dim3(256), 0, stream>>>(o1, ho2, wt + 1968, wt + 5808, hj2, 0);
  k_lnpart<<<dim3(NB * 4), dim3(256), 0, stream>>>(hj2, part);
  k_lnapply<<<dim3(250), dim3(256), 0, stream>>>(hj2, part, gamma + 80000, beta + 80000,
                                                 (float*)d_out);
}

// Round 18
// 251.140 us; speedup vs baseline: 1.0730x; 1.0730x over previous
//
#include <hip/hip_runtime.h>

// ---------------------------------------------------------------------------
// net_lstm: graph-constructor (topk-20 sparse adj) + per-node LSTM (bf16 MFMA)
//           + mixprop x2 (sparse gather + uniform-weight proj) + layernorm.
// Only layer j=2 of the 3 layers affects the output (reference overwrites h).
// ALL tensors are FLOAT32 on device. LSTM matmul in bf16 MFMA, rest fp32.
// k_lstm design notes (measured):
//  - 16 independent accumulators (64 AGPR) + 48 back-to-back MFMAs per step
//    beat a 16-AGPR low-ILP variant by 10% (r8 95.8 vs r9 105.5us).
//  - OCCUPANCY KNOB IS CLOSED: (256,4)->850MB spill (r7); (256,3)->7MB spill
//    +25% occupancy and still +11us SLOWER (r14). Stay (256,2).
//  - REGISTER-CACHING CLOSED TOO: r17's +32 VGPR Whh-tile cache hit the
//    128-VGPR allocation quantum -> 19MB spill +28us, AND perturbed k_adj's
//    co-compiled regalloc into a 52MB spill (rule #19). 124 VGPR is the cap.
//  - r10's raw asm("v_exp_f32") + weight pre-scaling produced zero output —
//    keep __expf; no hand-rolled trans asm.
// r18 = exact revert to r16 (best stable: ~250us).
// ---------------------------------------------------------------------------

typedef unsigned short u16;
typedef __attribute__((ext_vector_type(8))) short bf16x8;   // 8 bf16 = 4 VGPR (MFMA A/B frag)
typedef __attribute__((ext_vector_type(4))) float fx4;      // MFMA C/D frag

#define NB 64          // batch
#define NNODE 1000
#define TT 12
#define FF 32
#define HH 64
#define DD 40
#define TOPK_ 20
#define EPR2 22        // adjacency entries per row: topk + diagonal + 1 pad (16B align)

__device__ __forceinline__ float rcp_f(float x) { return __builtin_amdgcn_rcpf(x); }
__device__ __forceinline__ float tanh_f(float x) {          // NaN-safe: e>=0 always
  return fmaf(-2.0f, rcp_f(__expf(2.0f * x) + 1.0f), 1.0f);
}
__device__ __forceinline__ unsigned int cvt_pk(float lo, float hi) {
  unsigned int r;                                           // r = [bf16(hi)|bf16(lo)]
  asm("v_cvt_pk_bf16_f32 %0, %1, %2" : "=v"(r) : "v"(lo), "v"(hi));
  return r;
}
__device__ __forceinline__ bf16x8 cvt8(const float* p) {    // 8 fp32 -> bf16x8 (4 cvt_pk)
  union { unsigned int u[4]; bf16x8 v; } r;
  #pragma unroll
  for (int e = 0; e < 4; e++) r.u[e] = cvt_pk(p[2 * e], p[2 * e + 1]);
  return r.v;
}
__device__ __forceinline__ bf16x8 cvt8v(float4 a, float4 b) {
  union { unsigned int u[4]; bf16x8 v; } r;
  r.u[0] = cvt_pk(a.x, a.y); r.u[1] = cvt_pk(a.z, a.w);
  r.u[2] = cvt_pk(b.x, b.y); r.u[3] = cvt_pk(b.z, b.w);
  return r.v;
}

// ---------------- K3+K1: fused LSTM (blocks 0..999) & m1m2/prep (1000..1313) -
__global__ __launch_bounds__(256, 2)
void k_lstm(const float* __restrict__ x, const float* __restrict__ Wih,
            const float* __restrict__ Whh, const float* __restrict__ bih,
            const float* __restrict__ bhh, const float* __restrict__ lw2,
            const float* __restrict__ lb2, float* __restrict__ hj,
            // m1m2/prep path:
            const float* __restrict__ emb1, const float* __restrict__ emb2,
            const float* __restrict__ w1, const float* __restrict__ b1,
            const float* __restrict__ w2, const float* __restrict__ b2,
            float* __restrict__ m1, float* __restrict__ m2,
            const float* __restrict__ p1w, const float* __restrict__ p1b,
            const float* __restrict__ p2w, const float* __restrict__ p2b,
            float* __restrict__ wt) {
  int tid = threadIdx.x;
  if (blockIdx.x >= 1000) {              // ---- m1m2 / prep path ----
    int mb = blockIdx.x - 1000;
    if (mb == 313) {                     // prep: proj weights transposed
      for (int i = tid; i < 1152; i += 256) { int c = i / 32, o = i % 32; wt[784 + i] = p1w[o * 36 + c]; }
      if (tid < 32) wt[1936 + tid] = p1b[tid];
      for (int i = tid; i < 3840; i += 256) { int c = i / 40, o = i % 40; wt[1968 + i] = p2w[o * 96 + c]; }
      if (tid < 40) wt[5808 + tid] = p2b[tid];
      return;
    }
    int id = mb * 256 + tid;
    if (id >= 2 * NNODE * DD) return;
    int sel = id / (NNODE * DD);
    int r = id % (NNODE * DD);
    int i = r / DD, o = r % DD;
    const float4* emb = (const float4*)((sel ? emb2 : emb1) + i * DD);
    const float4* w = (const float4*)((sel ? w2 : w1) + o * DD);
    float s = (sel ? b2 : b1)[o];
    #pragma unroll
    for (int k4 = 0; k4 < DD / 4; k4++) {
      float4 a = emb[k4], b = w[k4];
      s = fmaf(a.x, b.x, s); s = fmaf(a.y, b.y, s);
      s = fmaf(a.z, b.z, s); s = fmaf(a.w, b.w, s);
    }
    (sel ? m2 : m1)[r] = tanh_f(3.0f * s);
    return;
  }
  // ---- LSTM path ----
  __shared__ __align__(16) u16 whf[2 * 16 * 64 * 8];  // Whh frags (32 KB)
  __shared__ __align__(16) u16 hsh[4][16][64];        // per-wave h shuttle (8 KB)
  __shared__ float lwsh[12 * 64];                     // lin_w2 [s][j] (3 KB)
  __shared__ float lbsh[12];
  int wave = tid >> 6, lane = tid & 63;
  int arow = lane & 15, kg = lane >> 4;

  for (int cc = tid; cc < 2 * 16 * 64; cc += 256) {
    int l = cc & 63, t16 = cc >> 6, ks = t16 >> 4, nt = t16 & 15;
    int row = (nt >> 2) * 64 + (l & 15) * 4 + (nt & 3);
    *(bf16x8*)&whf[cc * 8] = cvt8(Whh + row * 64 + ks * 32 + (l >> 4) * 8);
  }
  for (int i = tid; i < 768; i += 256) lwsh[i] = lw2[i];   // identity map
  if (tid < 12) lbsh[tid] = lb2[tid];
  __syncthreads();                                    // the ONLY block barrier

  bf16x8 wi[16];
  float biasv[16];
  #pragma unroll
  for (int nt = 0; nt < 16; nt++) {
    int row = (nt >> 2) * 64 + arow * 4 + (nt & 3);
    wi[nt] = cvt8(Wih + row * 32 + kg * 8);
    biasv[nt] = bih[row] + bhh[row];
  }

  int seq_base = blockIdx.x * 64 + wave * 16;
  const float* xb = x + (size_t)(seq_base + arow) * (TT * FF) + kg * 8;
  float cst[16];
  #pragma unroll
  for (int q = 0; q < 16; q++) cst[q] = 0.f;

  float4 xf0 = *(const float4*)(xb);                  // prefetch t=0
  float4 xf1 = *(const float4*)(xb + 4);

  auto STEP = [&](int t, bool first, float (&hq)[16]) {
    unsigned int zo = 0;                 // opaque zero: whf addrs loop-variant
    asm volatile("" : "+v"(zo));
    bf16x8 xa = cvt8v(xf0, xf1);
    if (t < TT - 1) {
      xf0 = *(const float4*)(xb + (t + 1) * FF);
      xf1 = *(const float4*)(xb + (t + 1) * FF + 4);
    }
    fx4 acc[16];
    #pragma unroll
    for (int nt = 0; nt < 16; nt++)
      acc[nt] = (fx4){biasv[nt], biasv[nt], biasv[nt], biasv[nt]};
    #pragma unroll
    for (int nt = 0; nt < 16; nt++)
      acc[nt] = __builtin_amdgcn_mfma_f32_16x16x32_bf16(xa, wi[nt], acc[nt], 0, 0, 0);
    if (!first) {
      asm volatile("" ::: "memory");
      bf16x8 ha0 = *(const bf16x8*)&hsh[wave][arow][kg * 8];
      bf16x8 ha1 = *(const bf16x8*)&hsh[wave][arow][32 + kg * 8];
      asm volatile("" ::: "memory");
      #pragma unroll
      for (int nt = 0; nt < 16; nt++) {
        bf16x8 wb = *(const bf16x8*)&whf[(nt * 64 + lane) * 8 + zo];
        acc[nt] = __builtin_amdgcn_mfma_f32_16x16x32_bf16(ha0, wb, acc[nt], 0, 0, 0);
      }
      #pragma unroll
      for (int nt = 0; nt < 16; nt++) {
        bf16x8 wb = *(const bf16x8*)&whf[((16 + nt) * 64 + lane) * 8 + zo];
        acc[nt] = __builtin_amdgcn_mfma_f32_16x16x32_bf16(ha1, wb, acc[nt], 0, 0, 0);
      }
    }
    #pragma unroll
    for (int i = 0; i < 4; i++) {
      #pragma unroll
      for (int njt = 0; njt < 4; njt++) {
        float iv = acc[njt][i], fv = acc[njt + 4][i];
        float gv = acc[njt + 8][i], ov = acc[njt + 12][i];
        float cpv = cst[i * 4 + njt];
        float ei = __expf(-iv), ef = __expf(-fv);
        float eg = __expf(2.0f * gv), eo = __expf(-ov);
        float A = 1.0f + ef;
        float B = (1.0f + ei) * (eg + 1.0f);
        float c = fmaf(cpv, B, (eg - 1.0f) * A) * rcp_f(A * B);
        cst[i * 4 + njt] = c;
        float ec = __expf(2.0f * c);
        hq[i * 4 + njt] = (ec - 1.0f) * rcp_f((ec + 1.0f) * (1.0f + eo));
      }
    }
  };

  #pragma unroll 1
  for (int t = 0; t < TT - 1; t++) {
    float hq[16];
    STEP(t, t == 0, hq);
    #pragma unroll
    for (int i = 0; i < 4; i++) {
      unsigned int p0 = cvt_pk(hq[i * 4 + 0], hq[i * 4 + 1]);
      unsigned int p1 = cvt_pk(hq[i * 4 + 2], hq[i * 4 + 3]);
      *(uint2*)&hsh[wave][kg * 4 + i][arow * 4] = make_uint2(p0, p1);
    }
  }
  float hq[16];
  STEP(TT - 1, false, hq);

  #pragma unroll
  for (int i = 0; i < 4; i++) {
    float a[12];
    #pragma unroll
    for (int s = 0; s < 12; s++) a[s] = 0.f;
    #pragma unroll
    for (int njt = 0; njt < 4; njt++) {
      float hv = hq[i * 4 + njt];
      #pragma unroll
      for (int s = 0; s < 12; s++)
        a[s] = fmaf(hv, lwsh[s * 64 + arow * 4 + njt], a[s]);
    }
    #pragma unroll
    for (int off = 1; off < 16; off <<= 1) {
      #pragma unroll
      for (int s = 0; s < 12; s++) a[s] += __shfl_xor(a[s], off);
    }
    float outv = a[0];                   // static select chain (rule #20)
    #pragma unroll
    for (int s = 1; s < 12; s++) outv = (arow == s) ? a[s] : outv;
    if (arow < 12) {
      int gseq = seq_base + kg * 4 + i;
      int bb = gseq / 1000, nn = gseq - bb * 1000;
      hj[(size_t)(bb * 12 + arow) * NNODE + nn] = outv + lbsh[arow];
    }
  }
}

// ---------------- K2: adjacency, 4 rows per block ----------------------------
__global__ void k_adj(const float* __restrict__ m1, const float* __restrict__ m2,
                      int2* __restrict__ pae) {
  int v0 = blockIdx.x * 4, tid = threadIdx.x;
  int lane = tid & 63, wave = tid >> 6;
  __shared__ float arow4[4][1024];                    // 16 KB
  __shared__ float m1v4[4][DD], m2v4[4][DD];
  for (int i = tid; i < 4 * DD; i += 256) {
    int r = i / DD, k = i % DD;
    m1v4[r][k] = m1[(v0 + r) * DD + k];
    m2v4[r][k] = m2[(v0 + r) * DD + k];
  }
  __syncthreads();
  for (int w = tid; w < NNODE; w += 256) {
    const float4* m2r = (const float4*)(m2 + w * DD);
    const float4* m1r = (const float4*)(m1 + w * DD);
    float4 a[10], bb[10];
    #pragma unroll
    for (int k4 = 0; k4 < 10; k4++) { a[k4] = m2r[k4]; bb[k4] = m1r[k4]; }
    #pragma unroll
    for (int r = 0; r < 4; r++) {
      float d1 = 0.f, d2 = 0.f;
      #pragma unroll
      for (int k4 = 0; k4 < 10; k4++) {
        d1 = fmaf(m1v4[r][k4 * 4 + 0], a[k4].x, d1);
        d1 = fmaf(m1v4[r][k4 * 4 + 1], a[k4].y, d1);
        d1 = fmaf(m1v4[r][k4 * 4 + 2], a[k4].z, d1);
        d1 = fmaf(m1v4[r][k4 * 4 + 3], a[k4].w, d1);
        d2 = fmaf(m2v4[r][k4 * 4 + 0], bb[k4].x, d2);
        d2 = fmaf(m2v4[r][k4 * 4 + 1], bb[k4].y, d2);
        d2 = fmaf(m2v4[r][k4 * 4 + 2], bb[k4].z, d2);
        d2 = fmaf(m2v4[r][k4 * 4 + 3], bb[k4].w, d2);
      }
      arow4[r][w] = fmaxf(tanh_f(3.0f * (d1 - d2)), 0.0f);
    }
  }
  __syncthreads();
  int v = v0 + wave, l = lane;           // wave r selects for row v0+r
  float rv[16];
  #pragma unroll
  for (int q = 0; q < 16; q++) {
    int idx = q * 64 + l;
    rv[q] = (idx < NNODE) ? arow4[wave][idx] : -2.f;
  }
  float rs = 1.f;                        // diagonal contributes 1
  float myv = 0.f; int myi = 0;          // lane l carries selected entry (l-1)
  #pragma unroll
  for (int sel = 0; sel < TOPK_; sel++) {
    float bv = rv[0]; int bi = l;
    #pragma unroll
    for (int q = 1; q < 16; q++) {
      int idx = q * 64 + l;
      if (rv[q] > bv) { bv = rv[q]; bi = idx; }   // ascending q => lowest idx on tie
    }
    #pragma unroll
    for (int off = 1; off < 64; off <<= 1) {
      float ov = __shfl_xor(bv, off); int oi = __shfl_xor(bi, off);
      if (ov > bv || (ov == bv && oi < bi)) { bv = ov; bi = oi; }
    }
    rs += bv;
    if (l == sel + 1) { myv = bv; myi = bi; }
    #pragma unroll
    for (int q = 0; q < 16; q++)
      if (q * 64 + l == bi) rv[q] = -2.f;         // invalidate winner
  }
  float inv = rcp_f(rs);
  if (l == 0)          pae[v * EPR2] = make_int2(v, __float_as_int(inv));
  else if (l <= TOPK_) pae[v * EPR2 + l] = make_int2(myi, __float_as_int(myv * inv));
  else if (l == 21)    pae[v * EPR2 + 21] = make_int2(v, 0);   // pad: val 0
}

// ---------------- K5/K7: mixprop propagation, 4 channels per block ----------
__global__ void k_prop4(const float* __restrict__ hin, const int2* __restrict__ pae,
                        float* __restrict__ ho, int C) {
  int NG = C >> 2;
  int b = blockIdx.x / NG, g = blockIdx.x % NG;
  int c0 = g * 4;
  __shared__ float r0c[4][1024];                      // 16 KB
  __shared__ float r1c[4][1024];                      // 16 KB
  int tid = threadIdx.x;
  const float* src = hin + ((size_t)b * C + c0) * NNODE;
  float* dst = ho + (size_t)b * 2 * C * NNODE;
  for (int n = tid; n < NNODE; n += 256) {
    r0c[0][n] = src[n];
    r0c[1][n] = src[NNODE + n];
    r0c[2][n] = src[2 * NNODE + n];
    r0c[3][n] = src[3 * NNODE + n];
  }
  __syncthreads();
  for (int n = tid; n < NNODE; n += 256) {
    const int4* pa4 = (const int4*)(pae + (size_t)n * EPR2);
    float s0 = 0.f, s1 = 0.f, s2 = 0.f, s3 = 0.f;
    #pragma unroll
    for (int e = 0; e < EPR2 / 2; e++) {
      int4 p = pa4[e];
      float av = __int_as_float(p.y);
      s0 = fmaf(av, r0c[0][p.x], s0); s1 = fmaf(av, r0c[1][p.x], s1);
      s2 = fmaf(av, r0c[2][p.x], s2); s3 = fmaf(av, r0c[3][p.x], s3);
      float aw = __int_as_float(p.w);
      s0 = fmaf(aw, r0c[0][p.z], s0); s1 = fmaf(aw, r0c[1][p.z], s1);
      s2 = fmaf(aw, r0c[2][p.z], s2); s3 = fmaf(aw, r0c[3][p.z], s3);
    }
    float h10 = fmaf(0.95f, s0, 0.05f * r0c[0][n]);
    float h11 = fmaf(0.95f, s1, 0.05f * r0c[1][n]);
    float h12 = fmaf(0.95f, s2, 0.05f * r0c[2][n]);
    float h13 = fmaf(0.95f, s3, 0.05f * r0c[3][n]);
    r1c[0][n] = h10; r1c[1][n] = h11; r1c[2][n] = h12; r1c[3][n] = h13;
    dst[(size_t)(c0 + 0) * NNODE + n] = h10;
    dst[(size_t)(c0 + 1) * NNODE + n] = h11;
    dst[(size_t)(c0 + 2) * NNODE + n] = h12;
    dst[(size_t)(c0 + 3) * NNODE + n] = h13;
  }
  __syncthreads();
  for (int n = tid; n < NNODE; n += 256) {
    const int4* pa4 = (const int4*)(pae + (size_t)n * EPR2);
    float s0 = 0.f, s1 = 0.f, s2 = 0.f, s3 = 0.f;
    #pragma unroll
    for (int e = 0; e < EPR2 / 2; e++) {
      int4 p = pa4[e];
      float av = __int_as_float(p.y);
      s0 = fmaf(av, r1c[0][p.x], s0); s1 = fmaf(av, r1c[1][p.x], s1);
      s2 = fmaf(av, r1c[2][p.x], s2); s3 = fmaf(av, r1c[3][p.x], s3);
      float aw = __int_as_float(p.w);
      s0 = fmaf(aw, r1c[0][p.z], s0); s1 = fmaf(aw, r1c[1][p.z], s1);
      s2 = fmaf(aw, r1c[2][p.z], s2); s3 = fmaf(aw, r1c[3][p.z], s3);
    }
    dst[(size_t)(C + c0 + 0) * NNODE + n] = fmaf(0.95f, s0, 0.05f * r0c[0][n]);
    dst[(size_t)(C + c0 + 1) * NNODE + n] = fmaf(0.95f, s1, 0.05f * r0c[1][n]);
    dst[(size_t)(C + c0 + 2) * NNODE + n] = fmaf(0.95f, s2, 0.05f * r0c[2][n]);
    dst[(size_t)(C + c0 + 3) * NNODE + n] = fmaf(0.95f, s3, 0.05f * r0c[3][n]);
  }
}

// ---------------- K6/K8: channel projection -----------------------------------
template <int C1, int COUT>
__global__ void k_proj(const float* __restrict__ src0, const float* __restrict__ src12,
                       const float* __restrict__ wt, const float* __restrict__ bb,
                       float* __restrict__ out, int relu) {
  int id = blockIdx.x * 256 + threadIdx.x;   // (b,n)
  int b = id / NNODE, n = id % NNODE;
  float acc[COUT];
  #pragma unroll
  for (int o = 0; o < COUT; o++) acc[o] = bb[o];
  for (int c = 0; c < C1; c++) {
    float hv = src0[(size_t)(b * C1 + c) * NNODE + n];
    #pragma unroll
    for (int o = 0; o < COUT; o++) acc[o] = fmaf(hv, wt[c * COUT + o], acc[o]);
  }
  for (int c = 0; c < 2 * C1; c++) {
    float hv = src12[(size_t)(b * 2 * C1 + c) * NNODE + n];
    #pragma unroll
    for (int o = 0; o < COUT; o++) acc[o] = fmaf(hv, wt[(C1 + c) * COUT + o], acc[o]);
  }
  #pragma unroll
  for (int o = 0; o < COUT; o++) {
    float vv = acc[o];
    if (relu) vv = fmaxf(vv, 0.f);
    out[(size_t)(b * COUT + o) * NNODE + n] = vv;
  }
}

// ---------------- K9a: LN partial stats (4 blocks per batch) -----------------
__global__ void k_lnpart(const float* __restrict__ hj2, float* __restrict__ part) {
  int b = blockIdx.x >> 2, qt = blockIdx.x & 3;
  int tid = threadIdx.x, lane = tid & 63, wave = tid >> 6;
  const float4* p = (const float4*)(hj2 + (size_t)b * DD * NNODE) + qt * 2500;
  float s = 0.f, q = 0.f;
  for (int i = tid; i < 2500; i += 256) {
    float4 vv = p[i];
    s += vv.x + vv.y + vv.z + vv.w;
    q = fmaf(vv.x, vv.x, q); q = fmaf(vv.y, vv.y, q);
    q = fmaf(vv.z, vv.z, q); q = fmaf(vv.w, vv.w, q);
  }
  for (int off = 32; off; off >>= 1) { s += __shfl_down(s, off); q += __shfl_down(q, off); }
  __shared__ float ss[4], sq[4];
  if (lane == 0) { ss[wave] = s; sq[wave] = q; }
  __syncthreads();
  if (tid == 0) {
    part[b * 8 + qt] = (ss[0] + ss[1]) + (ss[2] + ss[3]);
    part[b * 8 + 4 + qt] = (sq[0] + sq[1]) + (sq[2] + sq[3]);
  }
}

// ---------------- K9b: LN apply (250 blocks; folds 4 partials inline) --------
__global__ void k_lnapply(const float* __restrict__ hj2, const float* __restrict__ part,
                          const float* __restrict__ gamma, const float* __restrict__ beta,
                          float* __restrict__ out) {
  int id = blockIdx.x * 256 + threadIdx.x;   // (b,n)
  int b = id / NNODE, n = id % NNODE;
  float S = (part[b * 8 + 0] + part[b * 8 + 1]) + (part[b * 8 + 2] + part[b * 8 + 3]);
  float Q = (part[b * 8 + 4] + part[b * 8 + 5]) + (part[b * 8 + 6] + part[b * 8 + 7]);
  const float invN = 1.0f / (float)(DD * NNODE);
  float mu = S * invN;
  float var = Q * invN - mu * mu;
  float rstd = __builtin_amdgcn_rsqf(var + 1e-5f);
  size_t obase = (size_t)b * (NNODE * DD) + (size_t)n * DD;
  #pragma unroll
  for (int d0 = 0; d0 < DD / 4; d0++) {
    float tt[4];
    #pragma unroll
    for (int qq = 0; qq < 4; qq++) {
      int d = d0 * 4 + qq;
      float h0 = hj2[(size_t)(b * DD + d) * NNODE + n];
      tt[qq] = (h0 - mu) * rstd * gamma[d * NNODE + n] + beta[d * NNODE + n];
    }
    *(float4*)(out + obase + d0 * 4) = (float4){tt[0], tt[1], tt[2], tt[3]};
  }
}

// ---------------- workspace layout (fp32 words, flat) ------------------------
#define OFF_M1   0
#define OFF_M2   40000
#define OFF_PAE  80000
#define OFF_HJ   124000
#define OFF_HO1  892000
#define OFF_O1   2428000
#define OFF_HO2  4476000
#define OFF_HJ2  8572000
#define OFF_PART 11132000
#define OFF_WT   11132512

extern "C" void kernel_launch(void* const* d_in, const int* in_sizes, int n_in,
                              void* d_out, int out_size, void* d_ws, size_t ws_size,
                              hipStream_t stream) {
  (void)in_sizes; (void)n_in; (void)out_size; (void)ws_size;
  const float* x     = (const float*)d_in[0];
  const float* emb1  = (const float*)d_in[1];
  const float* emb2  = (const float*)d_in[2];
  const float* l1w   = (const float*)d_in[3];
  const float* l1b   = (const float*)d_in[4];
  const float* l2w   = (const float*)d_in[5];
  const float* l2b   = (const float*)d_in[6];
  const float* Wih   = (const float*)d_in[7];
  const float* Whh   = (const float*)d_in[8];
  const float* bih   = (const float*)d_in[9];
  const float* bhh   = (const float*)d_in[10];
  const float* lin_w = (const float*)d_in[11];
  const float* lin_b = (const float*)d_in[12];
  const float* mp1w  = (const float*)d_in[13];
  const float* mp1b  = (const float*)d_in[14];
  const float* mp2w  = (const float*)d_in[15];
  const float* mp2b  = (const float*)d_in[16];
  const float* gamma = (const float*)d_in[17];
  const float* beta  = (const float*)d_in[18];

  float* ws   = (float*)d_ws;
  float* m1   = ws + OFF_M1;
  float* m2   = ws + OFF_M2;
  int2*  pae  = (int2*)(ws + OFF_PAE);
  float* hj   = ws + OFF_HJ;
  float* ho1  = ws + OFF_HO1;
  float* o1   = ws + OFF_O1;
  float* ho2  = ws + OFF_HO2;
  float* hj2  = ws + OFF_HJ2;
  float* part = ws + OFF_PART;
  float* wt   = ws + OFF_WT;

  k_lstm<<<dim3(1314), dim3(256), 0, stream>>>(x, Wih, Whh, bih, bhh,
                                               lin_w + 1536, lin_b + 24, hj,
                                               emb1, emb2, l1w, l1b, l2w, l2b, m1, m2,
                                               mp1w + 2304, mp1b + 64,
                                               mp2w + 7680, mp2b + 80, wt);
  k_adj<<<dim3(250), dim3(256), 0, stream>>>(m1, m2, pae);
  k_prop4<<<dim3(64 * 3), dim3(256), 0, stream>>>(hj, pae, ho1, 12);
  k_proj<12, 32><<<dim3(250), dim3(256), 0, stream>>>(hj, ho1, wt + 784, wt + 1936, o1, 1);
  k_prop4<<<dim3(64 * 8), dim3(256), 0, stream>>>(o1, pae, ho2, 32);
  k_proj<32, 40><<<dim3(250), dim3(256), 0, stream>>>(o1, ho2, wt + 1968, wt + 5808, hj2, 0);
  k_lnpart<<<dim3(NB * 4), dim3(256), 0, stream>>>(hj2, part);
  k_lnapply<<<dim3(250), dim3(256), 0, stream>>>(hj2, part, gamma + 80000, beta + 80000,
                                                 (float*)d_out);
}

// Round 19
// 246.755 us; speedup vs baseline: 1.0920x; 1.0178x over previous
//
#include <hip/hip_runtime.h>

// ---------------------------------------------------------------------------
// net_lstm: graph-constructor (topk-20 sparse adj) + per-node LSTM (bf16 MFMA)
//           + mixprop x2 (sparse gather + uniform-weight proj) + layernorm.
// Only layer j=2 of the 3 layers affects the output (reference overwrites h).
// ALL tensors are FLOAT32 on device. LSTM matmul in bf16 MFMA, rest fp32.
// k_lstm design notes (measured):
//  - 16 independent accumulators (64 AGPR) + 48 back-to-back MFMAs per step
//    beat a 16-AGPR low-ILP variant by 10% (r8 95.8 vs r9 105.5us).
//  - OCCUPANCY KNOB IS CLOSED: (256,4)->850MB spill (r7); (256,3)->7MB spill
//    +25% occupancy and still +11us SLOWER (r14). Stay (256,2).
//  - REGISTER-CACHING CLOSED: r17's +32 VGPR Whh cache hit the 128-VGPR
//    quantum -> 19MB spill. 124 VGPR is the cap.
//  - r10's raw asm("v_exp_f32") + weight pre-scaling produced zero output —
//    keep __expf; no hand-rolled trans asm.
// r19: k_adj score loop DE-CACHED — r13's float4 a[10],bb[10] (80 VGPR) was
// spilling since introduction (r18 profile: VGPR 64, 52MB WRITE, 124us for
// a 0.16-GFLOP kernel). Now streams 2 float4/chunk into d1[4]/d2[4]
// accumulators (~30 VGPR demand, no spill). Same fma order = bit-identical.
// ---------------------------------------------------------------------------

typedef unsigned short u16;
typedef __attribute__((ext_vector_type(8))) short bf16x8;   // 8 bf16 = 4 VGPR (MFMA A/B frag)
typedef __attribute__((ext_vector_type(4))) float fx4;      // MFMA C/D frag

#define NB 64          // batch
#define NNODE 1000
#define TT 12
#define FF 32
#define HH 64
#define DD 40
#define TOPK_ 20
#define EPR2 22        // adjacency entries per row: topk + diagonal + 1 pad (16B align)

__device__ __forceinline__ float rcp_f(float x) { return __builtin_amdgcn_rcpf(x); }
__device__ __forceinline__ float tanh_f(float x) {          // NaN-safe: e>=0 always
  return fmaf(-2.0f, rcp_f(__expf(2.0f * x) + 1.0f), 1.0f);
}
__device__ __forceinline__ unsigned int cvt_pk(float lo, float hi) {
  unsigned int r;                                           // r = [bf16(hi)|bf16(lo)]
  asm("v_cvt_pk_bf16_f32 %0, %1, %2" : "=v"(r) : "v"(lo), "v"(hi));
  return r;
}
__device__ __forceinline__ bf16x8 cvt8(const float* p) {    // 8 fp32 -> bf16x8 (4 cvt_pk)
  union { unsigned int u[4]; bf16x8 v; } r;
  #pragma unroll
  for (int e = 0; e < 4; e++) r.u[e] = cvt_pk(p[2 * e], p[2 * e + 1]);
  return r.v;
}
__device__ __forceinline__ bf16x8 cvt8v(float4 a, float4 b) {
  union { unsigned int u[4]; bf16x8 v; } r;
  r.u[0] = cvt_pk(a.x, a.y); r.u[1] = cvt_pk(a.z, a.w);
  r.u[2] = cvt_pk(b.x, b.y); r.u[3] = cvt_pk(b.z, b.w);
  return r.v;
}

// ---------------- K3+K1: fused LSTM (blocks 0..999) & m1m2/prep (1000..1313) -
__global__ __launch_bounds__(256, 2)
void k_lstm(const float* __restrict__ x, const float* __restrict__ Wih,
            const float* __restrict__ Whh, const float* __restrict__ bih,
            const float* __restrict__ bhh, const float* __restrict__ lw2,
            const float* __restrict__ lb2, float* __restrict__ hj,
            // m1m2/prep path:
            const float* __restrict__ emb1, const float* __restrict__ emb2,
            const float* __restrict__ w1, const float* __restrict__ b1,
            const float* __restrict__ w2, const float* __restrict__ b2,
            float* __restrict__ m1, float* __restrict__ m2,
            const float* __restrict__ p1w, const float* __restrict__ p1b,
            const float* __restrict__ p2w, const float* __restrict__ p2b,
            float* __restrict__ wt) {
  int tid = threadIdx.x;
  if (blockIdx.x >= 1000) {              // ---- m1m2 / prep path ----
    int mb = blockIdx.x - 1000;
    if (mb == 313) {                     // prep: proj weights transposed
      for (int i = tid; i < 1152; i += 256) { int c = i / 32, o = i % 32; wt[784 + i] = p1w[o * 36 + c]; }
      if (tid < 32) wt[1936 + tid] = p1b[tid];
      for (int i = tid; i < 3840; i += 256) { int c = i / 40, o = i % 40; wt[1968 + i] = p2w[o * 96 + c]; }
      if (tid < 40) wt[5808 + tid] = p2b[tid];
      return;
    }
    int id = mb * 256 + tid;
    if (id >= 2 * NNODE * DD) return;
    int sel = id / (NNODE * DD);
    int r = id % (NNODE * DD);
    int i = r / DD, o = r % DD;
    const float4* emb = (const float4*)((sel ? emb2 : emb1) + i * DD);
    const float4* w = (const float4*)((sel ? w2 : w1) + o * DD);
    float s = (sel ? b2 : b1)[o];
    #pragma unroll
    for (int k4 = 0; k4 < DD / 4; k4++) {
      float4 a = emb[k4], b = w[k4];
      s = fmaf(a.x, b.x, s); s = fmaf(a.y, b.y, s);
      s = fmaf(a.z, b.z, s); s = fmaf(a.w, b.w, s);
    }
    (sel ? m2 : m1)[r] = tanh_f(3.0f * s);
    return;
  }
  // ---- LSTM path ----
  __shared__ __align__(16) u16 whf[2 * 16 * 64 * 8];  // Whh frags (32 KB)
  __shared__ __align__(16) u16 hsh[4][16][64];        // per-wave h shuttle (8 KB)
  __shared__ float lwsh[12 * 64];                     // lin_w2 [s][j] (3 KB)
  __shared__ float lbsh[12];
  int wave = tid >> 6, lane = tid & 63;
  int arow = lane & 15, kg = lane >> 4;

  for (int cc = tid; cc < 2 * 16 * 64; cc += 256) {
    int l = cc & 63, t16 = cc >> 6, ks = t16 >> 4, nt = t16 & 15;
    int row = (nt >> 2) * 64 + (l & 15) * 4 + (nt & 3);
    *(bf16x8*)&whf[cc * 8] = cvt8(Whh + row * 64 + ks * 32 + (l >> 4) * 8);
  }
  for (int i = tid; i < 768; i += 256) lwsh[i] = lw2[i];   // identity map
  if (tid < 12) lbsh[tid] = lb2[tid];
  __syncthreads();                                    // the ONLY block barrier

  bf16x8 wi[16];
  float biasv[16];
  #pragma unroll
  for (int nt = 0; nt < 16; nt++) {
    int row = (nt >> 2) * 64 + arow * 4 + (nt & 3);
    wi[nt] = cvt8(Wih + row * 32 + kg * 8);
    biasv[nt] = bih[row] + bhh[row];
  }

  int seq_base = blockIdx.x * 64 + wave * 16;
  const float* xb = x + (size_t)(seq_base + arow) * (TT * FF) + kg * 8;
  float cst[16];
  #pragma unroll
  for (int q = 0; q < 16; q++) cst[q] = 0.f;

  float4 xf0 = *(const float4*)(xb);                  // prefetch t=0
  float4 xf1 = *(const float4*)(xb + 4);

  auto STEP = [&](int t, bool first, float (&hq)[16]) {
    unsigned int zo = 0;                 // opaque zero: whf addrs loop-variant
    asm volatile("" : "+v"(zo));
    bf16x8 xa = cvt8v(xf0, xf1);
    if (t < TT - 1) {
      xf0 = *(const float4*)(xb + (t + 1) * FF);
      xf1 = *(const float4*)(xb + (t + 1) * FF + 4);
    }
    fx4 acc[16];
    #pragma unroll
    for (int nt = 0; nt < 16; nt++)
      acc[nt] = (fx4){biasv[nt], biasv[nt], biasv[nt], biasv[nt]};
    #pragma unroll
    for (int nt = 0; nt < 16; nt++)
      acc[nt] = __builtin_amdgcn_mfma_f32_16x16x32_bf16(xa, wi[nt], acc[nt], 0, 0, 0);
    if (!first) {
      asm volatile("" ::: "memory");
      bf16x8 ha0 = *(const bf16x8*)&hsh[wave][arow][kg * 8];
      bf16x8 ha1 = *(const bf16x8*)&hsh[wave][arow][32 + kg * 8];
      asm volatile("" ::: "memory");
      #pragma unroll
      for (int nt = 0; nt < 16; nt++) {
        bf16x8 wb = *(const bf16x8*)&whf[(nt * 64 + lane) * 8 + zo];
        acc[nt] = __builtin_amdgcn_mfma_f32_16x16x32_bf16(ha0, wb, acc[nt], 0, 0, 0);
      }
      #pragma unroll
      for (int nt = 0; nt < 16; nt++) {
        bf16x8 wb = *(const bf16x8*)&whf[((16 + nt) * 64 + lane) * 8 + zo];
        acc[nt] = __builtin_amdgcn_mfma_f32_16x16x32_bf16(ha1, wb, acc[nt], 0, 0, 0);
      }
    }
    #pragma unroll
    for (int i = 0; i < 4; i++) {
      #pragma unroll
      for (int njt = 0; njt < 4; njt++) {
        float iv = acc[njt][i], fv = acc[njt + 4][i];
        float gv = acc[njt + 8][i], ov = acc[njt + 12][i];
        float cpv = cst[i * 4 + njt];
        float ei = __expf(-iv), ef = __expf(-fv);
        float eg = __expf(2.0f * gv), eo = __expf(-ov);
        float A = 1.0f + ef;
        float B = (1.0f + ei) * (eg + 1.0f);
        float c = fmaf(cpv, B, (eg - 1.0f) * A) * rcp_f(A * B);
        cst[i * 4 + njt] = c;
        float ec = __expf(2.0f * c);
        hq[i * 4 + njt] = (ec - 1.0f) * rcp_f((ec + 1.0f) * (1.0f + eo));
      }
    }
  };

  #pragma unroll 1
  for (int t = 0; t < TT - 1; t++) {
    float hq[16];
    STEP(t, t == 0, hq);
    #pragma unroll
    for (int i = 0; i < 4; i++) {
      unsigned int p0 = cvt_pk(hq[i * 4 + 0], hq[i * 4 + 1]);
      unsigned int p1 = cvt_pk(hq[i * 4 + 2], hq[i * 4 + 3]);
      *(uint2*)&hsh[wave][kg * 4 + i][arow * 4] = make_uint2(p0, p1);
    }
  }
  float hq[16];
  STEP(TT - 1, false, hq);

  #pragma unroll
  for (int i = 0; i < 4; i++) {
    float a[12];
    #pragma unroll
    for (int s = 0; s < 12; s++) a[s] = 0.f;
    #pragma unroll
    for (int njt = 0; njt < 4; njt++) {
      float hv = hq[i * 4 + njt];
      #pragma unroll
      for (int s = 0; s < 12; s++)
        a[s] = fmaf(hv, lwsh[s * 64 + arow * 4 + njt], a[s]);
    }
    #pragma unroll
    for (int off = 1; off < 16; off <<= 1) {
      #pragma unroll
      for (int s = 0; s < 12; s++) a[s] += __shfl_xor(a[s], off);
    }
    float outv = a[0];                   // static select chain (rule #20)
    #pragma unroll
    for (int s = 1; s < 12; s++) outv = (arow == s) ? a[s] : outv;
    if (arow < 12) {
      int gseq = seq_base + kg * 4 + i;
      int bb = gseq / 1000, nn = gseq - bb * 1000;
      hj[(size_t)(bb * 12 + arow) * NNODE + nn] = outv + lbsh[arow];
    }
  }
}

// ---------------- K2: adjacency, 4 rows per block, STREAMED score loop -------
// Score phase streams the w-row 2 float4s at a time into 8 accumulators
// (no 80-VGPR row cache -> no spill; r18 showed 52MB scratch, 124us).
// Same fma order per dot product as before = bit-identical scores.
__global__ void k_adj(const float* __restrict__ m1, const float* __restrict__ m2,
                      int2* __restrict__ pae) {
  int v0 = blockIdx.x * 4, tid = threadIdx.x;
  int lane = tid & 63, wave = tid >> 6;
  __shared__ float arow4[4][1024];                    // 16 KB
  __shared__ float m1v4[4][DD], m2v4[4][DD];
  for (int i = tid; i < 4 * DD; i += 256) {
    int r = i / DD, k = i % DD;
    m1v4[r][k] = m1[(v0 + r) * DD + k];
    m2v4[r][k] = m2[(v0 + r) * DD + k];
  }
  __syncthreads();
  for (int w = tid; w < NNODE; w += 256) {
    const float4* m2r = (const float4*)(m2 + w * DD);
    const float4* m1r = (const float4*)(m1 + w * DD);
    float d1[4] = {0.f, 0.f, 0.f, 0.f};
    float d2[4] = {0.f, 0.f, 0.f, 0.f};
    #pragma unroll
    for (int k4 = 0; k4 < 10; k4++) {
      float4 a = m2r[k4], b = m1r[k4];
      #pragma unroll
      for (int r = 0; r < 4; r++) {
        d1[r] = fmaf(m1v4[r][k4 * 4 + 0], a.x, d1[r]);
        d1[r] = fmaf(m1v4[r][k4 * 4 + 1], a.y, d1[r]);
        d1[r] = fmaf(m1v4[r][k4 * 4 + 2], a.z, d1[r]);
        d1[r] = fmaf(m1v4[r][k4 * 4 + 3], a.w, d1[r]);
        d2[r] = fmaf(m2v4[r][k4 * 4 + 0], b.x, d2[r]);
        d2[r] = fmaf(m2v4[r][k4 * 4 + 1], b.y, d2[r]);
        d2[r] = fmaf(m2v4[r][k4 * 4 + 2], b.z, d2[r]);
        d2[r] = fmaf(m2v4[r][k4 * 4 + 3], b.w, d2[r]);
      }
    }
    #pragma unroll
    for (int r = 0; r < 4; r++)
      arow4[r][w] = fmaxf(tanh_f(3.0f * (d1[r] - d2[r])), 0.0f);
  }
  __syncthreads();
  int v = v0 + wave, l = lane;           // wave r selects for row v0+r
  float rv[16];
  #pragma unroll
  for (int q = 0; q < 16; q++) {
    int idx = q * 64 + l;
    rv[q] = (idx < NNODE) ? arow4[wave][idx] : -2.f;
  }
  float rs = 1.f;                        // diagonal contributes 1
  float myv = 0.f; int myi = 0;          // lane l carries selected entry (l-1)
  #pragma unroll
  for (int sel = 0; sel < TOPK_; sel++) {
    float bv = rv[0]; int bi = l;
    #pragma unroll
    for (int q = 1; q < 16; q++) {
      int idx = q * 64 + l;
      if (rv[q] > bv) { bv = rv[q]; bi = idx; }   // ascending q => lowest idx on tie
    }
    #pragma unroll
    for (int off = 1; off < 64; off <<= 1) {
      float ov = __shfl_xor(bv, off); int oi = __shfl_xor(bi, off);
      if (ov > bv || (ov == bv && oi < bi)) { bv = ov; bi = oi; }
    }
    rs += bv;
    if (l == sel + 1) { myv = bv; myi = bi; }
    #pragma unroll
    for (int q = 0; q < 16; q++)
      if (q * 64 + l == bi) rv[q] = -2.f;         // invalidate winner
  }
  float inv = rcp_f(rs);
  if (l == 0)          pae[v * EPR2] = make_int2(v, __float_as_int(inv));
  else if (l <= TOPK_) pae[v * EPR2 + l] = make_int2(myi, __float_as_int(myv * inv));
  else if (l == 21)    pae[v * EPR2 + 21] = make_int2(v, 0);   // pad: val 0
}

// ---------------- K5/K7: mixprop propagation, 4 channels per block ----------
__global__ void k_prop4(const float* __restrict__ hin, const int2* __restrict__ pae,
                        float* __restrict__ ho, int C) {
  int NG = C >> 2;
  int b = blockIdx.x / NG, g = blockIdx.x % NG;
  int c0 = g * 4;
  __shared__ float r0c[4][1024];                      // 16 KB
  __shared__ float r1c[4][1024];                      // 16 KB
  int tid = threadIdx.x;
  const float* src = hin + ((size_t)b * C + c0) * NNODE;
  float* dst = ho + (size_t)b * 2 * C * NNODE;
  for (int n = tid; n < NNODE; n += 256) {
    r0c[0][n] = src[n];
    r0c[1][n] = src[NNODE + n];
    r0c[2][n] = src[2 * NNODE + n];
    r0c[3][n] = src[3 * NNODE + n];
  }
  __syncthreads();
  for (int n = tid; n < NNODE; n += 256) {
    const int4* pa4 = (const int4*)(pae + (size_t)n * EPR2);
    float s0 = 0.f, s1 = 0.f, s2 = 0.f, s3 = 0.f;
    #pragma unroll
    for (int e = 0; e < EPR2 / 2; e++) {
      int4 p = pa4[e];
      float av = __int_as_float(p.y);
      s0 = fmaf(av, r0c[0][p.x], s0); s1 = fmaf(av, r0c[1][p.x], s1);
      s2 = fmaf(av, r0c[2][p.x], s2); s3 = fmaf(av, r0c[3][p.x], s3);
      float aw = __int_as_float(p.w);
      s0 = fmaf(aw, r0c[0][p.z], s0); s1 = fmaf(aw, r0c[1][p.z], s1);
      s2 = fmaf(aw, r0c[2][p.z], s2); s3 = fmaf(aw, r0c[3][p.z], s3);
    }
    float h10 = fmaf(0.95f, s0, 0.05f * r0c[0][n]);
    float h11 = fmaf(0.95f, s1, 0.05f * r0c[1][n]);
    float h12 = fmaf(0.95f, s2, 0.05f * r0c[2][n]);
    float h13 = fmaf(0.95f, s3, 0.05f * r0c[3][n]);
    r1c[0][n] = h10; r1c[1][n] = h11; r1c[2][n] = h12; r1c[3][n] = h13;
    dst[(size_t)(c0 + 0) * NNODE + n] = h10;
    dst[(size_t)(c0 + 1) * NNODE + n] = h11;
    dst[(size_t)(c0 + 2) * NNODE + n] = h12;
    dst[(size_t)(c0 + 3) * NNODE + n] = h13;
  }
  __syncthreads();
  for (int n = tid; n < NNODE; n += 256) {
    const int4* pa4 = (const int4*)(pae + (size_t)n * EPR2);
    float s0 = 0.f, s1 = 0.f, s2 = 0.f, s3 = 0.f;
    #pragma unroll
    for (int e = 0; e < EPR2 / 2; e++) {
      int4 p = pa4[e];
      float av = __int_as_float(p.y);
      s0 = fmaf(av, r1c[0][p.x], s0); s1 = fmaf(av, r1c[1][p.x], s1);
      s2 = fmaf(av, r1c[2][p.x], s2); s3 = fmaf(av, r1c[3][p.x], s3);
      float aw = __int_as_float(p.w);
      s0 = fmaf(aw, r1c[0][p.z], s0); s1 = fmaf(aw, r1c[1][p.z], s1);
      s2 = fmaf(aw, r1c[2][p.z], s2); s3 = fmaf(aw, r1c[3][p.z], s3);
    }
    dst[(size_t)(C + c0 + 0) * NNODE + n] = fmaf(0.95f, s0, 0.05f * r0c[0][n]);
    dst[(size_t)(C + c0 + 1) * NNODE + n] = fmaf(0.95f, s1, 0.05f * r0c[1][n]);
    dst[(size_t)(C + c0 + 2) * NNODE + n] = fmaf(0.95f, s2, 0.05f * r0c[2][n]);
    dst[(size_t)(C + c0 + 3) * NNODE + n] = fmaf(0.95f, s3, 0.05f * r0c[3][n]);
  }
}

// ---------------- K6/K8: channel projection -----------------------------------
template <int C1, int COUT>
__global__ void k_proj(const float* __restrict__ src0, const float* __restrict__ src12,
                       const float* __restrict__ wt, const float* __restrict__ bb,
                       float* __restrict__ out, int relu) {
  int id = blockIdx.x * 256 + threadIdx.x;   // (b,n)
  int b = id / NNODE, n = id % NNODE;
  float acc[COUT];
  #pragma unroll
  for (int o = 0; o < COUT; o++) acc[o] = bb[o];
  for (int c = 0; c < C1; c++) {
    float hv = src0[(size_t)(b * C1 + c) * NNODE + n];
    #pragma unroll
    for (int o = 0; o < COUT; o++) acc[o] = fmaf(hv, wt[c * COUT + o], acc[o]);
  }
  for (int c = 0; c < 2 * C1; c++) {
    float hv = src12[(size_t)(b * 2 * C1 + c) * NNODE + n];
    #pragma unroll
    for (int o = 0; o < COUT; o++) acc[o] = fmaf(hv, wt[(C1 + c) * COUT + o], acc[o]);
  }
  #pragma unroll
  for (int o = 0; o < COUT; o++) {
    float vv = acc[o];
    if (relu) vv = fmaxf(vv, 0.f);
    out[(size_t)(b * COUT + o) * NNODE + n] = vv;
  }
}

// ---------------- K9a: LN partial stats (4 blocks per batch) -----------------
__global__ void k_lnpart(const float* __restrict__ hj2, float* __restrict__ part) {
  int b = blockIdx.x >> 2, qt = blockIdx.x & 3;
  int tid = threadIdx.x, lane = tid & 63, wave = tid >> 6;
  const float4* p = (const float4*)(hj2 + (size_t)b * DD * NNODE) + qt * 2500;
  float s = 0.f, q = 0.f;
  for (int i = tid; i < 2500; i += 256) {
    float4 vv = p[i];
    s += vv.x + vv.y + vv.z + vv.w;
    q = fmaf(vv.x, vv.x, q); q = fmaf(vv.y, vv.y, q);
    q = fmaf(vv.z, vv.z, q); q = fmaf(vv.w, vv.w, q);
  }
  for (int off = 32; off; off >>= 1) { s += __shfl_down(s, off); q += __shfl_down(q, off); }
  __shared__ float ss[4], sq[4];
  if (lane == 0) { ss[wave] = s; sq[wave] = q; }
  __syncthreads();
  if (tid == 0) {
    part[b * 8 + qt] = (ss[0] + ss[1]) + (ss[2] + ss[3]);
    part[b * 8 + 4 + qt] = (sq[0] + sq[1]) + (sq[2] + sq[3]);
  }
}

// ---------------- K9b: LN apply (250 blocks; folds 4 partials inline) --------
__global__ void k_lnapply(const float* __restrict__ hj2, const float* __restrict__ part,
                          const float* __restrict__ gamma, const float* __restrict__ beta,
                          float* __restrict__ out) {
  int id = blockIdx.x * 256 + threadIdx.x;   // (b,n)
  int b = id / NNODE, n = id % NNODE;
  float S = (part[b * 8 + 0] + part[b * 8 + 1]) + (part[b * 8 + 2] + part[b * 8 + 3]);
  float Q = (part[b * 8 + 4] + part[b * 8 + 5]) + (part[b * 8 + 6] + part[b * 8 + 7]);
  const float invN = 1.0f / (float)(DD * NNODE);
  float mu = S * invN;
  float var = Q * invN - mu * mu;
  float rstd = __builtin_amdgcn_rsqf(var + 1e-5f);
  size_t obase = (size_t)b * (NNODE * DD) + (size_t)n * DD;
  #pragma unroll
  for (int d0 = 0; d0 < DD / 4; d0++) {
    float tt[4];
    #pragma unroll
    for (int qq = 0; qq < 4; qq++) {
      int d = d0 * 4 + qq;
      float h0 = hj2[(size_t)(b * DD + d) * NNODE + n];
      tt[qq] = (h0 - mu) * rstd * gamma[d * NNODE + n] + beta[d * NNODE + n];
    }
    *(float4*)(out + obase + d0 * 4) = (float4){tt[0], tt[1], tt[2], tt[3]};
  }
}

// ---------------- workspace layout (fp32 words, flat) ------------------------
#define OFF_M1   0
#define OFF_M2   40000
#define OFF_PAE  80000
#define OFF_HJ   124000
#define OFF_HO1  892000
#define OFF_O1   2428000
#define OFF_HO2  4476000
#define OFF_HJ2  8572000
#define OFF_PART 11132000
#define OFF_WT   11132512

extern "C" void kernel_launch(void* const* d_in, const int* in_sizes, int n_in,
                              void* d_out, int out_size, void* d_ws, size_t ws_size,
                              hipStream_t stream) {
  (void)in_sizes; (void)n_in; (void)out_size; (void)ws_size;
  const float* x     = (const float*)d_in[0];
  const float* emb1  = (const float*)d_in[1];
  const float* emb2  = (const float*)d_in[2];
  const float* l1w   = (const float*)d_in[3];
  const float* l1b   = (const float*)d_in[4];
  const float* l2w   = (const float*)d_in[5];
  const float* l2b   = (const float*)d_in[6];
  const float* Wih   = (const float*)d_in[7];
  const float* Whh   = (const float*)d_in[8];
  const float* bih   = (const float*)d_in[9];
  const float* bhh   = (const float*)d_in[10];
  const float* lin_w = (const float*)d_in[11];
  const float* lin_b = (const float*)d_in[12];
  const float* mp1w  = (const float*)d_in[13];
  const float* mp1b  = (const float*)d_in[14];
  const float* mp2w  = (const float*)d_in[15];
  const float* mp2b  = (const float*)d_in[16];
  const float* gamma = (const float*)d_in[17];
  const float* beta  = (const float*)d_in[18];

  float* ws   = (float*)d_ws;
  float* m1   = ws + OFF_M1;
  float* m2   = ws + OFF_M2;
  int2*  pae  = (int2*)(ws + OFF_PAE);
  float* hj   = ws + OFF_HJ;
  float* ho1  = ws + OFF_HO1;
  float* o1   = ws + OFF_O1;
  float* ho2  = ws + OFF_HO2;
  float* hj2  = ws + OFF_HJ2;
  float* part = ws + OFF_PART;
  float* wt   = ws + OFF_WT;

  k_lstm<<<dim3(1314), dim3(256), 0, stream>>>(x, Wih, Whh, bih, bhh,
                                               lin_w + 1536, lin_b + 24, hj,
                                               emb1, emb2, l1w, l1b, l2w, l2b, m1, m2,
                                               mp1w + 2304, mp1b + 64,
                                               mp2w + 7680, mp2b + 80, wt);
  k_adj<<<dim3(250), dim3(256), 0, stream>>>(m1, m2, pae);
  k_prop4<<<dim3(64 * 3), dim3(256), 0, stream>>>(hj, pae, ho1, 12);
  k_proj<12, 32><<<dim3(250), dim3(256), 0, stream>>>(hj, ho1, wt + 784, wt + 1936, o1, 1);
  k_prop4<<<dim3(64 * 8), dim3(256), 0, stream>>>(o1, pae, ho2, 32);
  k_proj<32, 40><<<dim3(250), dim3(256), 0, stream>>>(o1, ho2, wt + 1968, wt + 5808, hj2, 0);
  k_lnpart<<<dim3(NB * 4), dim3(256), 0, stream>>>(hj2, part);
  k_lnapply<<<dim3(250), dim3(256), 0, stream>>>(hj2, part, gamma + 80000, beta + 80000,
                                                 (float*)d_out);
}